// Round 3
// baseline (490.970 us; speedup 1.0000x reference)
//
#include <hip/hip_runtime.h>
#include <math.h>

#define B_ 8
#define C_ 64
#define H_ 128
#define W_ 128
#define O_ 64
#define HW_ (H_ * W_)
#define SP 68      // LDS slab stride (elems) for S tiles: 64 + 4 pad
#define OMS 29     // LDS stride for om rows (conflict-free: 29*delta % 32 != 0)

typedef short short4v __attribute__((ext_vector_type(4)));
typedef short short8v __attribute__((ext_vector_type(8)));
typedef float f32x4   __attribute__((ext_vector_type(4)));
typedef float f32x16  __attribute__((ext_vector_type(16)));

__device__ __forceinline__ unsigned pack_bf16_pair(unsigned u0, unsigned u1) {
    // low short = bf16(u0 value, trunc), high short = bf16(u1 value, trunc)
    return (u1 & 0xffff0000u) | (u0 >> 16);
}

// round-to-nearest-even bf16 hi/lo split (for static weights; high accuracy)
__device__ __forceinline__ void split_rtne(float v, short* hi, short* lo) {
    unsigned u = __float_as_uint(v);
    unsigned r = (u + 0x7fffu + ((u >> 16) & 1u)) & 0xffff0000u;
    *hi = (short)(r >> 16);
    float rem = v - __uint_as_float(r);
    unsigned u2 = __float_as_uint(rem);
    unsigned r2 = (u2 + 0x7fffu + ((u2 >> 16) & 1u));
    *lo = (short)(r2 >> 16);
}

// ws: Wchi[64*576], Wclo[64*576], Womhi[32*576], Womlo[32*576]  (all bf16-as-short)
// Wc  K-order: ck = k*64 + c     (k = 3x3 tap of main conv weight)
// Wom K-order: tk = tap*64 + c   (tap = 3x3 tap of offset/mask conv)
__global__ void prep_weights(const float* __restrict__ wc,
                             const float* __restrict__ wo,
                             const float* __restrict__ wm,
                             short* __restrict__ Wchi, short* __restrict__ Wclo,
                             short* __restrict__ Womhi, short* __restrict__ Womlo)
{
    int tid = blockIdx.x * blockDim.x + threadIdx.x;
    if (tid < 64 * 576) {
        int o = tid / 576, ck = tid % 576;
        int k = ck >> 6, c = ck & 63;
        float v = wc[(o * 64 + c) * 9 + k];
        split_rtne(v, &Wchi[tid], &Wclo[tid]);
    }
    if (tid < 32 * 576) {
        int n = tid / 576, tk = tid % 576;
        int tap = tk >> 6, c = tk & 63;
        float v = 0.f;
        if (n < 18)      v = wo[(n * 64 + c) * 9 + tap];
        else if (n < 27) v = wm[((n - 18) * 64 + c) * 9 + tap];
        split_rtne(v, &Womhi[tid], &Womlo[tid]);
    }
}

__global__ __launch_bounds__(256, 4) void deform_mfma(
    const float* __restrict__ x,
    const short* __restrict__ Wchi, const short* __restrict__ Wclo,
    const short* __restrict__ Womhi, const short* __restrict__ Womlo,
    float* __restrict__ out)
{
    __shared__ short Shi[64 * SP];
    __shared__ short Slo[64 * SP];
    __shared__ float omb[64 * OMS];

    const int t = threadIdx.x;
    const int lane = t & 63;
    const int wv = t >> 6;       // wave id 0..3
    const int px = lane;         // staging: lane -> pixel (contiguous gathers)
    const int g = wv;            // staging: wave -> c-range [g*16, g*16+16)

    const int blk = blockIdx.x;                 // 2048 blocks, 64 px each
    const int wcol0 = (blk & 1) << 6;           // 0 or 64
    const int h = (blk >> 1) & (H_ - 1);        // block-uniform row
    const int b = blk >> 8;
    const float* xb = x + (size_t)b * C_ * HW_;
    const int wcol = wcol0 + px;

    // ================= phase A: offset/mask conv via MFMA (bf16x3) =========
    f32x4 cv0 = {}, cv1 = {};
    {
        int ty = 0, tx = 0;
        for (int tap = 0; tap < 9; ++tap) {
            const int yy = h + ty - 1;
            const bool yok = (unsigned)yy < (unsigned)H_;
            const int xxr = wcol + tx - 1;
            const bool ok = yok && ((unsigned)xxr < (unsigned)W_);
            const int yyc = min(max(yy, 0), H_ - 1);
            const int xxc = min(max(xxr, 0), W_ - 1);
            const float* rp = xb + yyc * W_ + xxc;
#pragma unroll 1
            for (int i = 0; i < 4; ++i) {
                const int c0 = (g << 4) + (i << 2);
                const float* pc = rp + (size_t)c0 * HW_;
                float s0 = ok ? pc[0] : 0.f;
                float s1 = ok ? pc[HW_] : 0.f;
                float s2 = ok ? pc[2 * HW_] : 0.f;
                float s3 = ok ? pc[3 * HW_] : 0.f;
                unsigned u0 = __float_as_uint(s0), u1 = __float_as_uint(s1);
                unsigned u2 = __float_as_uint(s2), u3 = __float_as_uint(s3);
                uint2 hv, lv;
                hv.x = pack_bf16_pair(u0, u1);
                hv.y = pack_bf16_pair(u2, u3);
                lv.x = pack_bf16_pair(__float_as_uint(s0 - __uint_as_float(u0 & 0xffff0000u)),
                                      __float_as_uint(s1 - __uint_as_float(u1 & 0xffff0000u)));
                lv.y = pack_bf16_pair(__float_as_uint(s2 - __uint_as_float(u2 & 0xffff0000u)),
                                      __float_as_uint(s3 - __uint_as_float(u3 & 0xffff0000u)));
                *(uint2*)&Shi[px * SP + c0] = hv;
                *(uint2*)&Slo[px * SP + c0] = lv;
            }
            __syncthreads();
            {
                const int mrow = (wv << 4) + (lane & 15);
                const int kq = (lane >> 4) << 3;
                const int n0 = lane & 15;
#pragma unroll
                for (int s = 0; s < 2; ++s) {
                    const int koff = (s << 5) + kq;
                    short4v a0 = *(const short4v*)&Shi[mrow * SP + koff];
                    short4v a1 = *(const short4v*)&Shi[mrow * SP + koff + 4];
                    short4v l0 = *(const short4v*)&Slo[mrow * SP + koff];
                    short4v l1 = *(const short4v*)&Slo[mrow * SP + koff + 4];
                    short8v ahi = __builtin_shufflevector(a0, a1, 0, 1, 2, 3, 4, 5, 6, 7);
                    short8v alo = __builtin_shufflevector(l0, l1, 0, 1, 2, 3, 4, 5, 6, 7);
                    const int kg = tap * 64 + koff;
                    short8v bh0 = *(const short8v*)&Womhi[n0 * 576 + kg];
                    short8v bl0 = *(const short8v*)&Womlo[n0 * 576 + kg];
                    short8v bh1 = *(const short8v*)&Womhi[(n0 + 16) * 576 + kg];
                    short8v bl1 = *(const short8v*)&Womlo[(n0 + 16) * 576 + kg];
                    cv0 = __builtin_amdgcn_mfma_f32_16x16x32_bf16(ahi, bh0, cv0, 0, 0, 0);
                    cv0 = __builtin_amdgcn_mfma_f32_16x16x32_bf16(ahi, bl0, cv0, 0, 0, 0);
                    cv0 = __builtin_amdgcn_mfma_f32_16x16x32_bf16(alo, bh0, cv0, 0, 0, 0);
                    cv1 = __builtin_amdgcn_mfma_f32_16x16x32_bf16(ahi, bh1, cv1, 0, 0, 0);
                    cv1 = __builtin_amdgcn_mfma_f32_16x16x32_bf16(ahi, bl1, cv1, 0, 0, 0);
                    cv1 = __builtin_amdgcn_mfma_f32_16x16x32_bf16(alo, bh1, cv1, 0, 0, 0);
                }
            }
            __syncthreads();
            if (++tx == 3) { tx = 0; ++ty; }
        }
    }
    // scatter om (C-layout: col=lane&15 -> j, row=(lane>>4)*4+reg -> px) to LDS
    {
        const int j0 = lane & 15;
        const int pxo = (wv << 4) + ((lane >> 4) << 2);
#pragma unroll
        for (int r = 0; r < 4; ++r) {
            omb[(pxo + r) * OMS + j0] = cv0[r];
            if (j0 + 16 < OMS) omb[(pxo + r) * OMS + j0 + 16] = cv1[r];
        }
    }
    __syncthreads();

    // ================= phase B: deformable sampling + einsum MFMA ==========
    f32x16 acc = {};
    const int mhalf = wv & 1, nhalf = wv >> 1;
    const int mrow = (mhalf << 5) + (lane & 31);
    const int nrow = (nhalf << 5) + (lane & 31);
    const int kq2 = (lane >> 5) << 3;

    {
        int ki = 0, kj = 0;
        for (int k = 0; k < 9; ++k) {
            const float offy = omb[px * OMS + 2 * k];
            const float offx = omb[px * OMS + 2 * k + 1];
            const float mr = omb[px * OMS + 18 + k];
            const float mk = 1.f / (1.f + __expf(-mr));
            const float py = (float)(h + ki - 1) + offy;
            const float pxf = (float)(wcol + kj - 1) + offx;
            const float y0f = floorf(py), x0f = floorf(pxf);
            const int y0i = (int)y0f, x0i = (int)x0f;
            const int y1i = y0i + 1, x1i = x0i + 1;
            const float wy1 = py - y0f, wy0 = 1.f - wy1;
            const float wx1 = pxf - x0f, wx0 = 1.f - wx1;
            const bool vy0 = (unsigned)y0i < (unsigned)H_;
            const bool vy1 = (unsigned)y1i < (unsigned)H_;
            const bool vx0 = (unsigned)x0i < (unsigned)W_;
            const bool vx1 = (unsigned)x1i < (unsigned)W_;
            const int y0c = min(max(y0i, 0), H_ - 1), y1c = min(max(y1i, 0), H_ - 1);
            const int x0c = min(max(x0i, 0), W_ - 1), x1c = min(max(x1i, 0), W_ - 1);
            const float w00 = wy0 * wx0 * ((vy0 && vx0) ? mk : 0.f);
            const float w01 = wy0 * wx1 * ((vy0 && vx1) ? mk : 0.f);
            const float w10 = wy1 * wx0 * ((vy1 && vx0) ? mk : 0.f);
            const float w11 = wy1 * wx1 * ((vy1 && vx1) ? mk : 0.f);
            const int i00 = y0c * W_ + x0c;
            const int i01 = y0c * W_ + x1c;
            const int i10 = y1c * W_ + x0c;
            const int i11 = y1c * W_ + x1c;

#pragma unroll 1
            for (int i = 0; i < 4; ++i) {
                const int c0 = (g << 4) + (i << 2);
                const float* pc = xb + (size_t)c0 * HW_;
                float s0 = w00 * pc[i00] + w01 * pc[i01] + w10 * pc[i10] + w11 * pc[i11];
                pc += HW_;
                float s1 = w00 * pc[i00] + w01 * pc[i01] + w10 * pc[i10] + w11 * pc[i11];
                pc += HW_;
                float s2 = w00 * pc[i00] + w01 * pc[i01] + w10 * pc[i10] + w11 * pc[i11];
                pc += HW_;
                float s3 = w00 * pc[i00] + w01 * pc[i01] + w10 * pc[i10] + w11 * pc[i11];
                unsigned u0 = __float_as_uint(s0), u1 = __float_as_uint(s1);
                unsigned u2 = __float_as_uint(s2), u3 = __float_as_uint(s3);
                uint2 hv, lv;
                hv.x = pack_bf16_pair(u0, u1);
                hv.y = pack_bf16_pair(u2, u3);
                lv.x = pack_bf16_pair(__float_as_uint(s0 - __uint_as_float(u0 & 0xffff0000u)),
                                      __float_as_uint(s1 - __uint_as_float(u1 & 0xffff0000u)));
                lv.y = pack_bf16_pair(__float_as_uint(s2 - __uint_as_float(u2 & 0xffff0000u)),
                                      __float_as_uint(s3 - __uint_as_float(u3 & 0xffff0000u)));
                *(uint2*)&Shi[px * SP + c0] = hv;
                *(uint2*)&Slo[px * SP + c0] = lv;
            }
            __syncthreads();
#pragma unroll
            for (int s = 0; s < 4; ++s) {
                const int koff = (s << 4) + kq2;
                short4v a0 = *(const short4v*)&Shi[mrow * SP + koff];
                short4v a1 = *(const short4v*)&Shi[mrow * SP + koff + 4];
                short4v l0 = *(const short4v*)&Slo[mrow * SP + koff];
                short4v l1 = *(const short4v*)&Slo[mrow * SP + koff + 4];
                short8v ahi = __builtin_shufflevector(a0, a1, 0, 1, 2, 3, 4, 5, 6, 7);
                short8v alo = __builtin_shufflevector(l0, l1, 0, 1, 2, 3, 4, 5, 6, 7);
                const int kg = k * 64 + koff;
                short8v bh = *(const short8v*)&Wchi[nrow * 576 + kg];
                short8v bl = *(const short8v*)&Wclo[nrow * 576 + kg];
                acc = __builtin_amdgcn_mfma_f32_32x32x16_bf16(ahi, bh, acc, 0, 0, 0);
                acc = __builtin_amdgcn_mfma_f32_32x32x16_bf16(ahi, bl, acc, 0, 0, 0);
                acc = __builtin_amdgcn_mfma_f32_32x32x16_bf16(alo, bh, acc, 0, 0, 0);
            }
            __syncthreads();
            if (++kj == 3) { kj = 0; ++ki; }
        }
    }

    // ================= epilogue: store C (32x32 layout) ====================
    {
        float* ob = out + ((size_t)b * O_ + nrow) * HW_ + h * W_ + wcol0;
        const int rbase = ((lane >> 5) << 2) + (mhalf << 5);
#pragma unroll
        for (int q = 0; q < 4; ++q) {
            f32x4 v = {acc[4 * q], acc[4 * q + 1], acc[4 * q + 2], acc[4 * q + 3]};
            *(f32x4*)&ob[rbase + 8 * q] = v;
        }
    }
}

extern "C" void kernel_launch(void* const* d_in, const int* in_sizes, int n_in,
                              void* d_out, int out_size, void* d_ws, size_t ws_size,
                              hipStream_t stream) {
    const float* x      = (const float*)d_in[0];
    const float* w_conv = (const float*)d_in[1];
    const float* w_off  = (const float*)d_in[2];
    const float* w_msk  = (const float*)d_in[3];
    float* out = (float*)d_out;

    short* Wchi  = (short*)d_ws;            // 64*576
    short* Wclo  = Wchi + 64 * 576;
    short* Womhi = Wclo + 64 * 576;         // 32*576
    short* Womlo = Womhi + 32 * 576;

    prep_weights<<<144, 256, 0, stream>>>(w_conv, w_off, w_msk, Wchi, Wclo, Womhi, Womlo);

    deform_mfma<<<2048, 256, 0, stream>>>(x, Wchi, Wclo, Womhi, Womlo, out);
}

// Round 5
// 384.431 us; speedup vs baseline: 1.2771x; 1.2771x over previous
//
#include <hip/hip_runtime.h>
#include <math.h>

#define B_ 8
#define C_ 64
#define H_ 128
#define W_ 128
#define O_ 64
#define HW_ (H_ * W_)
#define SPH 72     // halfs per S-tile row: 64 + 8 pad (144B rows -> 16B-aligned b128, 2-way-max banks)
#define OMS 29     // floats per om row

typedef short    short8v __attribute__((ext_vector_type(8)));
typedef _Float16 half8v  __attribute__((ext_vector_type(8)));
typedef __fp16   fp16x2  __attribute__((ext_vector_type(2)));
typedef float    f32x4   __attribute__((ext_vector_type(4)));
typedef float    f32x16  __attribute__((ext_vector_type(16)));

__device__ __forceinline__ unsigned pack_bf16_pair(unsigned u0, unsigned u1) {
    return (u1 & 0xffff0000u) | (u0 >> 16);
}
__device__ __forceinline__ void split_rtne(float v, short* hi, short* lo) {
    unsigned u = __float_as_uint(v);
    unsigned r = (u + 0x7fffu + ((u >> 16) & 1u)) & 0xffff0000u;
    *hi = (short)(r >> 16);
    float rem = v - __uint_as_float(r);
    unsigned u2 = __float_as_uint(rem);
    unsigned r2 = (u2 + 0x7fffu + ((u2 >> 16) & 1u));
    *lo = (short)(r2 >> 16);
}

// ws: Wch[64*576] f16 ([o][k*64+c]), Womhi/Womlo[32*576] bf16 ([n][tap*64+c])
__global__ void prep_weights(const float* __restrict__ wc,
                             const float* __restrict__ wo,
                             const float* __restrict__ wm,
                             _Float16* __restrict__ Wch,
                             short* __restrict__ Womhi, short* __restrict__ Womlo)
{
    int tid = blockIdx.x * blockDim.x + threadIdx.x;
    if (tid < 64 * 576) {
        int o = tid / 576, ck = tid % 576;
        int k = ck >> 6, c = ck & 63;
        Wch[tid] = (_Float16)wc[(o * 64 + c) * 9 + k];
    }
    if (tid < 32 * 576) {
        int n = tid / 576, tk = tid % 576;
        int tap = tk >> 6, c = tk & 63;
        float v = 0.f;
        if (n < 18)      v = wo[(n * 64 + c) * 9 + tap];
        else if (n < 27) v = wm[((n - 18) * 64 + c) * 9 + tap];
        split_rtne(v, &Womhi[tid], &Womlo[tid]);
    }
}

__global__ __launch_bounds__(256, 4) void deform_mfma(
    const float* __restrict__ x,
    const _Float16* __restrict__ Wch,
    const short* __restrict__ Womhi, const short* __restrict__ Womlo,
    float* __restrict__ out)
{
    __shared__ _Float16 sb[2][64 * SPH];   // phase A: [0]=hi,[1]=lo; phase B: double buffer
    __shared__ float omb[64 * OMS];

    const int t = threadIdx.x;
    const int lane = t & 63;
    const int wv = t >> 6;
    const int px = lane;
    const int g = __builtin_amdgcn_readfirstlane(wv);

    const int blk = blockIdx.x;
    const int b = blk & 7;                 // XCD-batch swizzle: batch pinned to XCD
    const int rest = blk >> 3;
    const int wcol0 = (rest & 1) << 6;
    const int h = rest >> 1;
    const float* xb = x + (size_t)b * C_ * HW_;
    const int wcol = wcol0 + px;

    const float* bases[16];
#pragma unroll
    for (int j = 0; j < 16; ++j) bases[j] = xb + (size_t)(g * 16 + j) * HW_;

    // ================= phase A: offset/mask conv via MFMA (bf16x3) =========
    f32x4 cv0 = {}, cv1 = {};
    float av[16];
    float okn, okc;
    {
        int yy = h - 1, xx = wcol - 1;
        okn = (((unsigned)yy < (unsigned)H_) && ((unsigned)xx < (unsigned)W_)) ? 1.f : 0.f;
        int yyc = min(max(yy, 0), H_ - 1), xxc = min(max(xx, 0), W_ - 1);
        int voff = yyc * W_ + xxc;
#pragma unroll
        for (int j = 0; j < 16; ++j) av[j] = bases[j][voff];
    }
    const int mrowA = (wv << 4) + (lane & 15);
    const int kqA = (lane >> 4) << 3;
    const int n0 = lane & 15;

#pragma unroll 1
    for (int tap = 0; tap < 9; ++tap) {
        okc = okn;
#pragma unroll
        for (int i = 0; i < 4; ++i) {
            float s0 = av[4*i+0] * okc, s1 = av[4*i+1] * okc;
            float s2 = av[4*i+2] * okc, s3 = av[4*i+3] * okc;
            unsigned u0 = __float_as_uint(s0), u1 = __float_as_uint(s1);
            unsigned u2 = __float_as_uint(s2), u3 = __float_as_uint(s3);
            uint2 hv, lv;
            hv.x = pack_bf16_pair(u0, u1);
            hv.y = pack_bf16_pair(u2, u3);
            lv.x = pack_bf16_pair(__float_as_uint(s0 - __uint_as_float(u0 & 0xffff0000u)),
                                  __float_as_uint(s1 - __uint_as_float(u1 & 0xffff0000u)));
            lv.y = pack_bf16_pair(__float_as_uint(s2 - __uint_as_float(u2 & 0xffff0000u)),
                                  __float_as_uint(s3 - __uint_as_float(u3 & 0xffff0000u)));
            const int off = px * SPH + (g << 4) + (i << 2);
            *(uint2*)&sb[0][off] = hv;
            *(uint2*)&sb[1][off] = lv;
        }
        if (tap < 8) {   // prefetch next tap's (coalesced) loads; fly across barrier
            int tn = tap + 1, ty = tn / 3, tx = tn - ty * 3;
            int yy = h + ty - 1, xx = wcol + tx - 1;
            okn = (((unsigned)yy < (unsigned)H_) && ((unsigned)xx < (unsigned)W_)) ? 1.f : 0.f;
            int yyc = min(max(yy, 0), H_ - 1), xxc = min(max(xx, 0), W_ - 1);
            int voff = yyc * W_ + xxc;
#pragma unroll
            for (int j = 0; j < 16; ++j) av[j] = bases[j][voff];
        }
        __builtin_amdgcn_s_waitcnt(0xC07F);   // lgkmcnt(0) only — vm loads stay in flight
        __builtin_amdgcn_s_barrier();
#pragma unroll
        for (int s = 0; s < 2; ++s) {
            const int koff = (s << 5) + kqA;
            short8v ahi = *(const short8v*)&sb[0][mrowA * SPH + koff];
            short8v alo = *(const short8v*)&sb[1][mrowA * SPH + koff];
            const int kg = tap * 64 + koff;
            short8v bh0 = *(const short8v*)&Womhi[n0 * 576 + kg];
            short8v bl0 = *(const short8v*)&Womlo[n0 * 576 + kg];
            short8v bh1 = *(const short8v*)&Womhi[(n0 + 16) * 576 + kg];
            short8v bl1 = *(const short8v*)&Womlo[(n0 + 16) * 576 + kg];
            cv0 = __builtin_amdgcn_mfma_f32_16x16x32_bf16(ahi, bh0, cv0, 0, 0, 0);
            cv0 = __builtin_amdgcn_mfma_f32_16x16x32_bf16(ahi, bl0, cv0, 0, 0, 0);
            cv0 = __builtin_amdgcn_mfma_f32_16x16x32_bf16(alo, bh0, cv0, 0, 0, 0);
            cv1 = __builtin_amdgcn_mfma_f32_16x16x32_bf16(ahi, bh1, cv1, 0, 0, 0);
            cv1 = __builtin_amdgcn_mfma_f32_16x16x32_bf16(ahi, bl1, cv1, 0, 0, 0);
            cv1 = __builtin_amdgcn_mfma_f32_16x16x32_bf16(alo, bh1, cv1, 0, 0, 0);
        }
        __builtin_amdgcn_s_barrier();   // reads done (lgkm drained by MFMA use) -> safe to rewrite
    }

    // scatter om (C-layout: col=lane&15 -> j, row=(lane>>4)*4+r -> px-within-16)
    {
        const int j0 = lane & 15;
        const int pxo = (wv << 4) + ((lane >> 4) << 2);
#pragma unroll
        for (int r = 0; r < 4; ++r) {
            omb[(pxo + r) * OMS + j0] = cv0[r];
            if (j0 < 13) omb[(pxo + r) * OMS + j0 + 16] = cv1[r];
        }
    }
    __builtin_amdgcn_s_waitcnt(0xC07F);
    __builtin_amdgcn_s_barrier();

    // ================= phase B: sampling + einsum (fp16 MFMA, pipelined) ====
    f32x16 acc = {};
    const int mhalf = wv & 1, nhalf = wv >> 1;
    const int mrow = (mhalf << 5) + (lane & 31);
    const int nrow = (nhalf << 5) + (lane & 31);
    const int kq2 = (lane >> 5) << 3;

    float v[64];
    float w00n, w01n, w10n, w11n;

    auto compute_issue = [&](int k) {
        const float offy = omb[px * OMS + 2 * k];
        const float offx = omb[px * OMS + 2 * k + 1];
        const float mr = omb[px * OMS + 18 + k];
        const float mk = 1.f / (1.f + __expf(-mr));
        const int ki = k / 3, kj = k - ki * 3;
        const float py = (float)(h + ki - 1) + offy;
        const float pxf = (float)(wcol + kj - 1) + offx;
        const float y0f = floorf(py), x0f = floorf(pxf);
        const int y0i = (int)y0f, x0i = (int)x0f;
        const int y1i = y0i + 1, x1i = x0i + 1;
        const float wy1 = py - y0f, wy0 = 1.f - wy1;
        const float wx1 = pxf - x0f, wx0 = 1.f - wx1;
        const bool vy0 = (unsigned)y0i < (unsigned)H_;
        const bool vy1 = (unsigned)y1i < (unsigned)H_;
        const bool vx0 = (unsigned)x0i < (unsigned)W_;
        const bool vx1 = (unsigned)x1i < (unsigned)W_;
        const int y0c = min(max(y0i, 0), H_ - 1), y1c = min(max(y1i, 0), H_ - 1);
        const int x0c = min(max(x0i, 0), W_ - 1), x1c = min(max(x1i, 0), W_ - 1);
        w00n = wy0 * wx0 * ((vy0 && vx0) ? mk : 0.f);
        w01n = wy0 * wx1 * ((vy0 && vx1) ? mk : 0.f);
        w10n = wy1 * wx0 * ((vy1 && vx0) ? mk : 0.f);
        w11n = wy1 * wx1 * ((vy1 && vx1) ? mk : 0.f);
        const int i00 = y0c * W_ + x0c;
        const int i01 = y0c * W_ + x1c;
        const int i10 = y1c * W_ + x0c;
        const int i11 = y1c * W_ + x1c;
#pragma unroll
        for (int j = 0; j < 16; ++j) {
            const float* bj = bases[j];
            v[4*j+0] = bj[i00];
            v[4*j+1] = bj[i01];
            v[4*j+2] = bj[i10];
            v[4*j+3] = bj[i11];
        }
    };

    compute_issue(0);
#pragma unroll 1
    for (int k = 0; k < 9; ++k) {
        const float w00c = w00n, w01c = w01n, w10c = w10n, w11c = w11n;
        _Float16* sbw = sb[k & 1];
#pragma unroll
        for (int i = 0; i < 4; ++i) {
            float s0 = w00c*v[16*i+0]  + w01c*v[16*i+1]  + w10c*v[16*i+2]  + w11c*v[16*i+3];
            float s1 = w00c*v[16*i+4]  + w01c*v[16*i+5]  + w10c*v[16*i+6]  + w11c*v[16*i+7];
            float s2 = w00c*v[16*i+8]  + w01c*v[16*i+9]  + w10c*v[16*i+10] + w11c*v[16*i+11];
            float s3 = w00c*v[16*i+12] + w01c*v[16*i+13] + w10c*v[16*i+14] + w11c*v[16*i+15];
            fp16x2 p01 = __builtin_amdgcn_cvt_pkrtz(s0, s1);
            fp16x2 p23 = __builtin_amdgcn_cvt_pkrtz(s2, s3);
            const int off = px * SPH + (g << 4) + (i << 2);
            *(fp16x2*)&sbw[off] = p01;
            *(fp16x2*)&sbw[off + 2] = p23;
        }
        if (k < 8) compute_issue(k + 1);      // next tap's 64 gathers fly across barrier+MFMA
        __builtin_amdgcn_s_waitcnt(0xC07F);   // lgkm only
        __builtin_amdgcn_s_barrier();
        const _Float16* sbr = sb[k & 1];
#pragma unroll
        for (int s = 0; s < 4; ++s) {
            const int koff = (s << 4) + kq2;
            half8v a  = *(const half8v*)&sbr[mrow * SPH + koff];
            half8v bw = *(const half8v*)&Wch[nrow * 576 + k * 64 + koff];
            acc = __builtin_amdgcn_mfma_f32_32x32x16_f16(a, bw, acc, 0, 0, 0);
        }
        // no trailing barrier: buf[k&1] next overwritten at k+2, after barrier k+1
    }

    // ================= epilogue: store C (32x32 layout, verified R3) =======
    {
        float* ob = out + ((size_t)b * O_ + nrow) * HW_ + h * W_ + wcol0;
        const int rbase = ((lane >> 5) << 2) + (mhalf << 5);
#pragma unroll
        for (int q = 0; q < 4; ++q) {
            f32x4 vv = {acc[4*q], acc[4*q+1], acc[4*q+2], acc[4*q+3]};
            *(f32x4*)&ob[rbase + 8*q] = vv;
        }
    }
}

extern "C" void kernel_launch(void* const* d_in, const int* in_sizes, int n_in,
                              void* d_out, int out_size, void* d_ws, size_t ws_size,
                              hipStream_t stream) {
    const float* x      = (const float*)d_in[0];
    const float* w_conv = (const float*)d_in[1];
    const float* w_off  = (const float*)d_in[2];
    const float* w_msk  = (const float*)d_in[3];
    float* out = (float*)d_out;

    _Float16* Wch = (_Float16*)d_ws;          // 64*576 halfs
    short* Womhi  = (short*)(Wch + 64 * 576); // 32*576
    short* Womlo  = Womhi + 32 * 576;

    prep_weights<<<144, 256, 0, stream>>>(w_conv, w_off, w_msk, Wch, Womhi, Womlo);

    deform_mfma<<<2048, 256, 0, stream>>>(x, Wch, Womhi, Womlo, out);
}

// Round 6
// 378.960 us; speedup vs baseline: 1.2956x; 1.0144x over previous
//
#include <hip/hip_runtime.h>
#include <math.h>

#define B_ 8
#define C_ 64
#define H_ 128
#define W_ 128
#define O_ 64
#define HW_ (H_ * W_)
#define OMS 29     // floats per om row (odd stride -> conflict-free b32)

typedef short    short8v __attribute__((ext_vector_type(8)));
typedef _Float16 half8v  __attribute__((ext_vector_type(8)));
typedef __fp16   fp16x2  __attribute__((ext_vector_type(2)));
typedef float    f32x4   __attribute__((ext_vector_type(4)));
typedef float    f32x16  __attribute__((ext_vector_type(16)));
typedef unsigned uint4v  __attribute__((ext_vector_type(4)));

// XOR-granule swizzle: row of 64 halfs = 8 granules of 16B; physical granule = logical ^ (row&7).
// Conflict-free for b128 reads/writes (lanes 0..7 cover all 32 banks), keeps 16B alignment.
__device__ __forceinline__ int swz(int row, int col) {
    return (row << 6) + ((((col >> 3) ^ (row & 7)) << 3)) + (col & 7);
}

__device__ __forceinline__ unsigned pack_bf16_pair(unsigned u0, unsigned u1) {
    return (u1 & 0xffff0000u) | (u0 >> 16);
}
__device__ __forceinline__ void split_rtne(float v, short* hi, short* lo) {
    unsigned u = __float_as_uint(v);
    unsigned r = (u + 0x7fffu + ((u >> 16) & 1u)) & 0xffff0000u;
    *hi = (short)(r >> 16);
    float rem = v - __uint_as_float(r);
    unsigned u2 = __float_as_uint(rem);
    unsigned r2 = (u2 + 0x7fffu + ((u2 >> 16) & 1u));
    *lo = (short)(r2 >> 16);
}

// ws: Wch[64*576] f16 ([o][k*64+c]), Womhi/Womlo[32*576] bf16 ([n][tap*64+c])
__global__ void prep_weights(const float* __restrict__ wc,
                             const float* __restrict__ wo,
                             const float* __restrict__ wm,
                             _Float16* __restrict__ Wch,
                             short* __restrict__ Womhi, short* __restrict__ Womlo)
{
    int tid = blockIdx.x * blockDim.x + threadIdx.x;
    if (tid < 64 * 576) {
        int o = tid / 576, ck = tid % 576;
        int k = ck >> 6, c = ck & 63;
        Wch[tid] = (_Float16)wc[(o * 64 + c) * 9 + k];
    }
    if (tid < 32 * 576) {
        int n = tid / 576, tk = tid % 576;
        int tap = tk >> 6, c = tk & 63;
        float v = 0.f;
        if (n < 18)      v = wo[(n * 64 + c) * 9 + tap];
        else if (n < 27) v = wm[((n - 18) * 64 + c) * 9 + tap];
        split_rtne(v, &Womhi[tid], &Womlo[tid]);
    }
}

__global__ __launch_bounds__(256, 4) void deform_mfma(
    const float* __restrict__ x,
    const _Float16* __restrict__ Wch,
    const short* __restrict__ Womhi, const short* __restrict__ Womlo,
    float* __restrict__ out)
{
    __shared__ _Float16 sb[2][64 * 64];   // phase A: [0]=hi,[1]=lo; phase B: double buffer (16 KB)
    __shared__ float omb[64 * OMS];

    const int t = threadIdx.x;
    const int lane = t & 63;
    const int wv = t >> 6;
    const int px = lane;
    const int g = __builtin_amdgcn_readfirstlane(wv);

    const int blk = blockIdx.x;
    const int b = blk & 7;                 // XCD-batch swizzle: batch pinned to XCD (R5: FETCH 860->17 MB)
    const int rest = blk >> 3;
    const int wcol0 = (rest & 1) << 6;
    const int h = rest >> 1;
    const float* xb = x + (size_t)b * C_ * HW_;
    const float* xg = xb + (size_t)(g * 16) * HW_;   // wave-uniform channel-group base (SGPR)
    const int wcol = wcol0 + px;

    // ================= phase A: offset/mask conv via MFMA (bf16x3) =========
    f32x4 cv0 = {}, cv1 = {};
    float av[16];
    float okn;
    {
        int yy = h - 1, xx = wcol - 1;
        okn = (((unsigned)yy < (unsigned)H_) && ((unsigned)xx < (unsigned)W_)) ? 1.f : 0.f;
        int yyc = min(max(yy, 0), H_ - 1), xxc = min(max(xx, 0), W_ - 1);
        int voff = yyc * W_ + xxc;
#pragma unroll
        for (int j = 0; j < 16; ++j) av[j] = xg[(size_t)j * HW_ + voff];
    }
    const int mrowA = (wv << 4) + (lane & 15);
    const int kqA = (lane >> 4) << 3;
    const int n0 = lane & 15;

#pragma unroll 1
    for (int tap = 0; tap < 9; ++tap) {
        const float okc = okn;
#pragma unroll
        for (int i = 0; i < 4; ++i) {
            float s0 = av[4*i+0] * okc, s1 = av[4*i+1] * okc;
            float s2 = av[4*i+2] * okc, s3 = av[4*i+3] * okc;
            unsigned u0 = __float_as_uint(s0), u1 = __float_as_uint(s1);
            unsigned u2 = __float_as_uint(s2), u3 = __float_as_uint(s3);
            uint2 hv, lv;
            hv.x = pack_bf16_pair(u0, u1);
            hv.y = pack_bf16_pair(u2, u3);
            lv.x = pack_bf16_pair(__float_as_uint(s0 - __uint_as_float(u0 & 0xffff0000u)),
                                  __float_as_uint(s1 - __uint_as_float(u1 & 0xffff0000u)));
            lv.y = pack_bf16_pair(__float_as_uint(s2 - __uint_as_float(u2 & 0xffff0000u)),
                                  __float_as_uint(s3 - __uint_as_float(u3 & 0xffff0000u)));
            const int off = swz(px, (g << 4) + (i << 2));
            *(uint2*)&sb[0][off] = hv;
            *(uint2*)&sb[1][off] = lv;
        }
        if (tap < 8) {   // prefetch next tap's (coalesced) loads; fly across barrier
            int tn = tap + 1, ty = tn / 3, tx = tn - ty * 3;
            int yy = h + ty - 1, xx = wcol + tx - 1;
            okn = (((unsigned)yy < (unsigned)H_) && ((unsigned)xx < (unsigned)W_)) ? 1.f : 0.f;
            int yyc = min(max(yy, 0), H_ - 1), xxc = min(max(xx, 0), W_ - 1);
            int voff = yyc * W_ + xxc;
#pragma unroll
            for (int j = 0; j < 16; ++j) av[j] = xg[(size_t)j * HW_ + voff];
        }
        __builtin_amdgcn_s_waitcnt(0xC07F);   // lgkmcnt(0) only — vm loads stay in flight
        __builtin_amdgcn_s_barrier();
#pragma unroll
        for (int s = 0; s < 2; ++s) {
            const int koff = (s << 5) + kqA;
            short8v ahi = *(const short8v*)&sb[0][swz(mrowA, koff)];
            short8v alo = *(const short8v*)&sb[1][swz(mrowA, koff)];
            const int kg = tap * 64 + koff;
            short8v bh0 = *(const short8v*)&Womhi[n0 * 576 + kg];
            short8v bl0 = *(const short8v*)&Womlo[n0 * 576 + kg];
            short8v bh1 = *(const short8v*)&Womhi[(n0 + 16) * 576 + kg];
            short8v bl1 = *(const short8v*)&Womlo[(n0 + 16) * 576 + kg];
            cv0 = __builtin_amdgcn_mfma_f32_16x16x32_bf16(ahi, bh0, cv0, 0, 0, 0);
            cv0 = __builtin_amdgcn_mfma_f32_16x16x32_bf16(ahi, bl0, cv0, 0, 0, 0);
            cv0 = __builtin_amdgcn_mfma_f32_16x16x32_bf16(alo, bh0, cv0, 0, 0, 0);
            cv1 = __builtin_amdgcn_mfma_f32_16x16x32_bf16(ahi, bh1, cv1, 0, 0, 0);
            cv1 = __builtin_amdgcn_mfma_f32_16x16x32_bf16(ahi, bl1, cv1, 0, 0, 0);
            cv1 = __builtin_amdgcn_mfma_f32_16x16x32_bf16(alo, bh1, cv1, 0, 0, 0);
        }
        __builtin_amdgcn_s_barrier();   // reads consumed (lgkm drained before MFMA use) -> safe rewrite
    }

    // scatter om (C-layout: col=lane&15 -> j, row=(lane>>4)*4+r -> px-within-16)
    {
        const int j0 = lane & 15;
        const int pxo = (wv << 4) + ((lane >> 4) << 2);
#pragma unroll
        for (int r = 0; r < 4; ++r) {
            omb[(pxo + r) * OMS + j0] = cv0[r];
            if (j0 < 13) omb[(pxo + r) * OMS + j0 + 16] = cv1[r];
        }
    }
    __builtin_amdgcn_s_waitcnt(0xC07F);
    __builtin_amdgcn_s_barrier();

    // ================= phase B: sampling + einsum (fp16 MFMA, pipelined) ====
    f32x16 acc = {};
    const int mhalf = wv & 1, nhalf = wv >> 1;
    const int mrow = (mhalf << 5) + (lane & 31);
    const int nrow = (nhalf << 5) + (lane & 31);
    const int kq2 = (lane >> 5) << 3;

    unsigned pnl[8];   // packed fp16 samples for the upcoming tap (8 regs, not 64!)

    auto sample_tap = [&](int k) {
        const float offy = omb[px * OMS + 2 * k];
        const float offx = omb[px * OMS + 2 * k + 1];
        const float mr = omb[px * OMS + 18 + k];
        const float mk = 1.f / (1.f + __expf(-mr));
        const int ki = k / 3, kj = k - ki * 3;
        const float py = (float)(h + ki - 1) + offy;
        const float pxf = (float)(wcol + kj - 1) + offx;
        const float y0f = floorf(py), x0f = floorf(pxf);
        const int y0i = (int)y0f, x0i = (int)x0f;
        const int y1i = y0i + 1, x1i = x0i + 1;
        const float wy1 = py - y0f, wy0 = 1.f - wy1;
        const float wx1 = pxf - x0f, wx0 = 1.f - wx1;
        const bool vy0 = (unsigned)y0i < (unsigned)H_;
        const bool vy1 = (unsigned)y1i < (unsigned)H_;
        const bool vx0 = (unsigned)x0i < (unsigned)W_;
        const bool vx1 = (unsigned)x1i < (unsigned)W_;
        const int y0c = min(max(y0i, 0), H_ - 1), y1c = min(max(y1i, 0), H_ - 1);
        const int x0c = min(max(x0i, 0), W_ - 1), x1c = min(max(x1i, 0), W_ - 1);
        const float w00 = wy0 * wx0 * ((vy0 && vx0) ? mk : 0.f);
        const float w01 = wy0 * wx1 * ((vy0 && vx1) ? mk : 0.f);
        const float w10 = wy1 * wx0 * ((vy1 && vx0) ? mk : 0.f);
        const float w11 = wy1 * wx1 * ((vy1 && vx1) ? mk : 0.f);
        const int i00 = y0c * W_ + x0c;
        const int i01 = y0c * W_ + x1c;
        const int i10 = y1c * W_ + x0c;
        const int i11 = y1c * W_ + x1c;

        // 4 chunks x 4 channels, 2-deep pipeline: issue chunk c+1 loads before combining chunk c.
        // Peak live gather regs = 32 (vs 64 in R5 which spilled to scratch).
        float tb[32];
#pragma unroll
        for (int j = 0; j < 4; ++j) {
            const float* bj = xg + (size_t)j * HW_;
            tb[4*j+0] = bj[i00]; tb[4*j+1] = bj[i01];
            tb[4*j+2] = bj[i10]; tb[4*j+3] = bj[i11];
        }
#pragma unroll
        for (int c = 0; c < 4; ++c) {
            if (c < 3) {
                const float* bc = xg + (size_t)((c + 1) * 4) * HW_;
#pragma unroll
                for (int j = 0; j < 4; ++j) {
                    const float* bj = bc + (size_t)j * HW_;
                    const int o = 16 * ((c + 1) & 1) + 4 * j;
                    tb[o+0] = bj[i00]; tb[o+1] = bj[i01];
                    tb[o+2] = bj[i10]; tb[o+3] = bj[i11];
                }
            }
            const int o = 16 * (c & 1);
            float s0 = w00*tb[o+0]  + w01*tb[o+1]  + w10*tb[o+2]  + w11*tb[o+3];
            float s1 = w00*tb[o+4]  + w01*tb[o+5]  + w10*tb[o+6]  + w11*tb[o+7];
            float s2 = w00*tb[o+8]  + w01*tb[o+9]  + w10*tb[o+10] + w11*tb[o+11];
            float s3 = w00*tb[o+12] + w01*tb[o+13] + w10*tb[o+14] + w11*tb[o+15];
            fp16x2 p01 = __builtin_amdgcn_cvt_pkrtz(s0, s1);
            fp16x2 p23 = __builtin_amdgcn_cvt_pkrtz(s2, s3);
            pnl[2*c]   = __builtin_bit_cast(unsigned, p01);
            pnl[2*c+1] = __builtin_bit_cast(unsigned, p23);
        }
    };

    sample_tap(0);
#pragma unroll 1
    for (int k = 0; k < 9; ++k) {
        _Float16* sbw = sb[k & 1];
        uint4v pa = {pnl[0], pnl[1], pnl[2], pnl[3]};
        uint4v pb = {pnl[4], pnl[5], pnl[6], pnl[7]};
        *(uint4v*)&sbw[swz(px, (g << 4))]     = pa;
        *(uint4v*)&sbw[swz(px, (g << 4) + 8)] = pb;
        if (k < 8) sample_tap(k + 1);         // gathers overlap within; stores carry 8 regs only
        __builtin_amdgcn_s_waitcnt(0xC07F);   // lgkm only — vm loads keep flying
        __builtin_amdgcn_s_barrier();
        const _Float16* sbr = sb[k & 1];
#pragma unroll
        for (int s = 0; s < 4; ++s) {
            const int koff = (s << 4) + kq2;
            half8v a  = *(const half8v*)&sbr[swz(mrow, koff)];
            half8v bw = *(const half8v*)&Wch[nrow * 576 + k * 64 + koff];
            acc = __builtin_amdgcn_mfma_f32_32x32x16_f16(a, bw, acc, 0, 0, 0);
        }
        // no trailing barrier: buf[k&1] next overwritten at k+2, after barrier k+1
    }

    // ================= epilogue: store C (32x32 layout, verified R3) =======
    {
        float* ob = out + ((size_t)b * O_ + nrow) * HW_ + h * W_ + wcol0;
        const int rbase = ((lane >> 5) << 2) + (mhalf << 5);
#pragma unroll
        for (int q = 0; q < 4; ++q) {
            f32x4 vv = {acc[4*q], acc[4*q+1], acc[4*q+2], acc[4*q+3]};
            *(f32x4*)&ob[rbase + 8*q] = vv;
        }
    }
}

extern "C" void kernel_launch(void* const* d_in, const int* in_sizes, int n_in,
                              void* d_out, int out_size, void* d_ws, size_t ws_size,
                              hipStream_t stream) {
    const float* x      = (const float*)d_in[0];
    const float* w_conv = (const float*)d_in[1];
    const float* w_off  = (const float*)d_in[2];
    const float* w_msk  = (const float*)d_in[3];
    float* out = (float*)d_out;

    _Float16* Wch = (_Float16*)d_ws;          // 64*576 halfs
    short* Womhi  = (short*)(Wch + 64 * 576); // 32*576
    short* Womlo  = Womhi + 32 * 576;

    prep_weights<<<144, 256, 0, stream>>>(w_conv, w_off, w_msk, Wch, Womhi, Womlo);

    deform_mfma<<<2048, 256, 0, stream>>>(x, Wch, Womhi, Womlo, out);
}